// Round 12
// baseline (392.143 us; speedup 1.0000x reference)
//
#include <hip/hip_runtime.h>
#include <math.h>

// CapsuleLayer dynamic routing. B=256, IN=1152, K=8, J=10, D=16, 3 passes.
//
// 4 kernels:
//  prep_all : (r7/r10/r11-verified) W -> wht bf16 [i][jd][k]*0.25
//             (k-replication: 4 K-quads read the same 8-k fragment ->
//             u = 4*(x*W/4)); x -> xht bf16 [i][b][k]. Also zeroes the
//             3x16 last-block counters (replay-safe).
//  caps_pass<P>: grid (48 i-slabs x 16 b-tiles), 256 thr = 4 waves.
//             Same verified compute as r11 (MFMA fragment math, in-lane
//             softmax without max-sub, 4-wave LDS tree reduce, slab store).
//             THEN fused squash via split-K last-block: threadfence +
//             per-btile atomic counter; 48th block reduces the 48 slabs for
//             its 16 batches (fixed order -> deterministic) + squash ->
//             vdot_g (P0: =v0, P1: +=v1) or out (P2).
// Algebra: logits at pass t = (sum of previous v)·u_hat; pass 0 c = 0.1.

typedef float f32x4 __attribute__((ext_vector_type(4)));
typedef short bf16x8 __attribute__((ext_vector_type(8)));

#define B_TOT 256
#define IN_CAPS 1152
#define OUT_CAPS 10
#define JD 160

#define NSLAB 48
#define IPB 24             // i per block
#define CHI 12             // i per W chunk (2 chunks)
#define REDS 164

#define WHT_BYTES (1152ull * 160 * 8 * 2)             // 2,949,120
#define XHT_BYTES (1152ull * 256 * 8 * 2)             // 4,718,592
#define SP_BYTES  ((size_t)NSLAB * B_TOT * JD * 4)    // 7,864,320
#define VD_BYTES  ((size_t)B_TOT * JD * 4)            // 163,840
#define CNT_BYTES (3 * 16 * 4)
#define WS_NEED   (WHT_BYTES + XHT_BYTES + SP_BYTES + VD_BYTES + CNT_BYTES)

static __device__ __forceinline__ unsigned f2bf(float f) {
    unsigned u = __float_as_uint(f);
    return (u + 0x7FFFu + ((u >> 16) & 1u)) >> 16;
}

// ---------------- coalesced preps (r7/r10/r11-verified) ----------------
#define PREPW_BLOCKS 288   // 4 i each
#define PREPX_BLOCKS 288   // 16 i x 64 b each

__global__ __launch_bounds__(256)
void prep_all(const float* __restrict__ x, const float* __restrict__ W,
              unsigned* __restrict__ whu, unsigned* __restrict__ xhu,
              int* __restrict__ cnt) {
    __shared__ __align__(16) float lds[64 * 132];   // 33,792 B
    const int bid = blockIdx.x, t = threadIdx.x;

    if (bid == 0 && t < 48) cnt[t] = 0;             // reset last-block counters

    if (bid < PREPW_BLOCKS) {
        const int i0 = bid * 4;
        const f32x4* src = (const f32x4*)(W + (size_t)i0 * 1280);
        for (int c = t; c < 1280; c += 256)
            *(f32x4*)(lds + c * 4) = src[c];          // coalesced read
        __syncthreads();
        for (int c = t; c < 2560; c += 256) {
            const int i_l = c / 640, p = c % 640;
            const int jd = p >> 2, kp = p & 3;        // k = 2*kp
            const int j = jd >> 4, d = jd & 15;
            const float* base = lds + i_l * 1280 + j * 128 + d;
            const unsigned lo = f2bf(base[(2 * kp) * 16] * 0.25f);
            const unsigned hi = f2bf(base[(2 * kp + 1) * 16] * 0.25f);
            whu[(size_t)i0 * 640 + c] = lo | (hi << 16);   // coalesced write
        }
    } else {
        const int bx = bid - PREPW_BLOCKS;
        const int it = bx >> 2;          // 72 i-tiles
        const int bt = bx & 3;           // 4 b-tiles of 64
        const int i0 = it * 16, b0 = bt * 64;
        for (int c = t; c < 2048; c += 256) {
            const int bl = c >> 5, cf = c & 31;
            f32x4 v = *(const f32x4*)(x + (size_t)(b0 + bl) * 9216 + i0 * 8 + cf * 4);
            *(f32x4*)(lds + bl * 132 + cf * 4) = v;   // coalesced read
        }
        __syncthreads();
        for (int c = t; c < 1024; c += 256) {
            const int i_l = c >> 6, b_l = c & 63;
            const float* r = lds + b_l * 132 + i_l * 8;
            uint4 o;
            o.x = f2bf(r[0]) | (f2bf(r[1]) << 16);
            o.y = f2bf(r[2]) | (f2bf(r[3]) << 16);
            o.z = f2bf(r[4]) | (f2bf(r[5]) << 16);
            o.w = f2bf(r[6]) | (f2bf(r[7]) << 16);
            ((uint4*)xhu)[(size_t)(i0 + i_l) * 256 + b0 + b_l] = o;  // 1KB runs
        }
    }
}

// ---------------- routing pass with fused last-block squash ----------------
template<int PASS>
__global__ __launch_bounds__(256, 3)
void caps_pass(const unsigned short* __restrict__ wht,
               const unsigned short* __restrict__ xht,
               float* __restrict__ vdot_g,
               float* __restrict__ s_part,
               float* __restrict__ out,
               int* __restrict__ cnt) {
    __shared__ __align__(16) unsigned short wsl[CHI * 160 * 8];  // 30,720 B
    __shared__ __align__(16) unsigned short xsl[IPB * 16 * 8];   //  6,144 B
    __shared__ int isLast;
    float* red = (float*)wsl;   // aliased after compute (needs 20,992 B)

    const int t = threadIdx.x;
    const int l = t & 63;
    const int w = t >> 6;              // wave 0..3 (splits i)
    const int m = l & 15;              // b in tile / A-row / C-col
    const int q = l >> 4;              // k-quad (replicated) / d-quad (out)
    const int islab = blockIdx.x;      // 0..47
    const int btile = blockIdx.y;      // 0..15
    const int b0 = btile * 16;
    const int b = b0 + m;
    const int i0 = islab * IPB;

    // ---- stage x slab once: 24 i x 16 b ----
    {
        uint4* dX = (uint4*)xsl;
        for (int c = t; c < IPB * 16; c += 256) {
            const int il = c >> 4, bl = c & 15;
            dX[c] = ((const uint4*)xht)[(size_t)(i0 + il) * 256 + b0 + bl];
        }
    }

    // vdot fragments (i-invariant) from global (L2-hot), PASS >= 1
    f32x4 vd[10];
    if (PASS > 0) {
        #pragma unroll
        for (int jt = 0; jt < 10; ++jt)
            vd[jt] = *(const f32x4*)(vdot_g + (size_t)b * JD + jt * 16 + q * 4);
    }

    f32x4 s[10];
    #pragma unroll
    for (int jt = 0; jt < 10; ++jt) s[jt] = (f32x4){0.f, 0.f, 0.f, 0.f};

    // ---- 2 W chunks of 12 i ----
    #pragma unroll 1
    for (int ch = 0; ch < 2; ++ch) {
        __syncthreads();    // prev chunk reads done (also orders xsl writes)
        {
            const uint4* srcW = (const uint4*)wht + (size_t)(i0 + ch * CHI) * 160;
            uint4* dW = (uint4*)wsl;
            for (int c = t; c < CHI * 160; c += 256) dW[c] = srcW[c];
        }
        __syncthreads();

        #pragma unroll 1
        for (int ii = 0; ii < 3; ++ii) {
            const int il = w * 3 + ii;                 // 0..11 within chunk
            const bf16x8 xb = *(const bf16x8*)(xsl + ((ch * CHI + il) * 16 + m) * 8);

            if (PASS == 0) {
                #pragma unroll
                for (int jt = 0; jt < 10; ++jt) {
                    const bf16x8 af = *(const bf16x8*)(wsl + (il * 160 + jt * 16 + m) * 8);
                    s[jt] = __builtin_amdgcn_mfma_f32_16x16x32_bf16(af, xb, s[jt], 0, 0, 0);
                }
            } else {
                f32x4 u[10];
                #pragma unroll
                for (int jt = 0; jt < 10; ++jt) {
                    const bf16x8 af = *(const bf16x8*)(wsl + (il * 160 + jt * 16 + m) * 8);
                    u[jt] = __builtin_amdgcn_mfma_f32_16x16x32_bf16(
                                af, xb, (f32x4){0.f, 0.f, 0.f, 0.f}, 0, 0, 0);
                }
                float L[10];
                #pragma unroll
                for (int jt = 0; jt < 10; ++jt) {
                    const f32x4 p = vd[jt] * u[jt];
                    float e = (p.x + p.y) + (p.z + p.w);
                    e += __shfl_xor(e, 16);
                    e += __shfl_xor(e, 32);
                    L[jt] = e;
                }
                float Z = 0.f;
                #pragma unroll
                for (int jt = 0; jt < 10; ++jt) { L[jt] = __expf(L[jt]); Z += L[jt]; }
                const float inv = 1.0f / Z;
                #pragma unroll
                for (int jt = 0; jt < 10; ++jt) s[jt] += (L[jt] * inv) * u[jt];
            }
        }
    }

    if (PASS == 0) {
        #pragma unroll
        for (int jt = 0; jt < 10; ++jt) s[jt] *= 0.1f;
    }

    // ---- 4-wave tree reduce through LDS (red aliases wsl) ----
    __syncthreads();
    if (w >= 2) {
        float* rp = red + (w - 2) * (16 * REDS) + m * REDS + q * 4;
        #pragma unroll
        for (int jt = 0; jt < 10; ++jt) *(f32x4*)(rp + jt * 16) = s[jt];
    }
    __syncthreads();
    if (w < 2) {
        const float* rp = red + w * (16 * REDS) + m * REDS + q * 4;
        #pragma unroll
        for (int jt = 0; jt < 10; ++jt) s[jt] += *(const f32x4*)(rp + jt * 16);
    }
    __syncthreads();
    if (w == 1) {
        float* rp = red + m * REDS + q * 4;
        #pragma unroll
        for (int jt = 0; jt < 10; ++jt) *(f32x4*)(rp + jt * 16) = s[jt];
    }
    __syncthreads();
    if (w == 0) {
        const float* rp = red + m * REDS + q * 4;
        #pragma unroll
        for (int jt = 0; jt < 10; ++jt) s[jt] += *(const f32x4*)(rp + jt * 16);
        float* sp = s_part + ((size_t)islab * B_TOT + b) * JD;
        #pragma unroll
        for (int jt = 0; jt < 10; ++jt)
            *(f32x4*)(sp + jt * 16 + q * 4) = s[jt];
    }

    // ---- fused squash: last block per btile reduces all 48 slabs ----
    __threadfence();                               // release our slab stores
    __syncthreads();                               // all lanes' stores fenced
    if (t == 0)
        isLast = (atomicAdd(&cnt[PASS * 16 + btile], 1) == NSLAB - 1);
    __syncthreads();
    if (!isLast) return;
    __threadfence();                               // acquire others' slabs

    // 2560 outputs for this btile; thread handles 10 (coalesced), fixed order
    float acc[10];
    #pragma unroll
    for (int c = 0; c < 10; ++c) acc[c] = 0.f;
    #pragma unroll 4
    for (int p = 0; p < NSLAB; ++p) {
        const float* sp = s_part + (size_t)p * (B_TOT * JD) + b0 * JD;
        #pragma unroll
        for (int c = 0; c < 10; ++c) acc[c] += sp[c * 256 + t];
    }
    #pragma unroll
    for (int c = 0; c < 10; ++c) {
        const float sv = acc[c];
        float tt = sv * sv;                        // d = (c*256+t)&15 = t&15
        tt += __shfl_xor(tt, 1);
        tt += __shfl_xor(tt, 2);
        tt += __shfl_xor(tt, 4);
        tt += __shfl_xor(tt, 8);
        const float sc = tt / (1.0f + tt) / sqrtf(tt + 1e-7f);
        const float v = sc * sv;
        const int e = b0 * JD + c * 256 + t;
        if (PASS == 0)      vdot_g[e] = v;
        else if (PASS == 1) vdot_g[e] += v;
        else                out[e] = v;
    }
}

// ---------- fallback: round-1 fused kernel (ws too small; shouldn't happen) ----------
#define FB_NGROUPS 32
#define FB_THREADS (FB_NGROUPS * 16)
#define FB_ITERS (IN_CAPS / FB_NGROUPS)
__global__ __launch_bounds__(FB_THREADS)
void caps_routing_kernel(const float* __restrict__ x, const float* __restrict__ W,
                         float* __restrict__ out) {
    __shared__ __align__(16) float xsf[IN_CAPS * 8];
    __shared__ float sredf[FB_NGROUPS * JD];
    __shared__ float vdot_lds[JD];
    const int b = blockIdx.x, tid = threadIdx.x;
    const int g = tid >> 4, d = tid & 15;
    {
        const float4* xg = reinterpret_cast<const float4*>(x + (size_t)b * IN_CAPS * 8);
        float4* xl = reinterpret_cast<float4*>(xsf);
        for (int t = tid; t < IN_CAPS * 2; t += FB_THREADS) xl[t] = xg[t];
    }
    __syncthreads();
    for (int pass = 0; pass < 3; ++pass) {
        float vdot_reg[OUT_CAPS];
        if (pass > 0) {
            #pragma unroll
            for (int j = 0; j < OUT_CAPS; ++j) vdot_reg[j] = vdot_lds[j * 16 + d];
        }
        float s_loc[OUT_CAPS];
        #pragma unroll
        for (int j = 0; j < OUT_CAPS; ++j) s_loc[j] = 0.f;
        for (int it = 0; it < FB_ITERS; ++it) {
            const int i = it * FB_NGROUPS + g;
            float xk[8];
            {
                const float4* xr = reinterpret_cast<const float4*>(xsf + i * 8);
                float4 a0 = xr[0], a1 = xr[1];
                xk[0]=a0.x; xk[1]=a0.y; xk[2]=a0.z; xk[3]=a0.w;
                xk[4]=a1.x; xk[5]=a1.y; xk[6]=a1.z; xk[7]=a1.w;
            }
            const float* wpf = W + (size_t)i * 1280 + d;
            float u[OUT_CAPS];
            #pragma unroll
            for (int j = 0; j < OUT_CAPS; ++j) {
                float acc = 0.f;
                #pragma unroll
                for (int k = 0; k < 8; ++k) acc = fmaf(xk[k], wpf[j * 128 + k * 16], acc);
                u[j] = acc;
            }
            if (pass == 0) {
                #pragma unroll
                for (int j = 0; j < OUT_CAPS; ++j) s_loc[j] = fmaf(0.1f, u[j], s_loc[j]);
            } else {
                float logit[OUT_CAPS];
                #pragma unroll
                for (int j = 0; j < OUT_CAPS; ++j) {
                    float t2 = vdot_reg[j] * u[j];
                    t2 += __shfl_xor(t2, 1); t2 += __shfl_xor(t2, 2);
                    t2 += __shfl_xor(t2, 4); t2 += __shfl_xor(t2, 8);
                    logit[j] = t2;
                }
                float mm = logit[0];
                #pragma unroll
                for (int j = 1; j < OUT_CAPS; ++j) mm = fmaxf(mm, logit[j]);
                float Z = 0.f, e[OUT_CAPS];
                #pragma unroll
                for (int j = 0; j < OUT_CAPS; ++j) { e[j] = expf(logit[j] - mm); Z += e[j]; }
                const float invZ = 1.0f / Z;
                #pragma unroll
                for (int j = 0; j < OUT_CAPS; ++j) s_loc[j] = fmaf(e[j] * invZ, u[j], s_loc[j]);
            }
        }
        #pragma unroll
        for (int j = 0; j < OUT_CAPS; ++j) sredf[g * JD + j * 16 + d] = s_loc[j];
        __syncthreads();
        if (tid < JD) {
            float sv = 0.f;
            #pragma unroll 8
            for (int gg = 0; gg < FB_NGROUPS; ++gg) sv += sredf[gg * JD + tid];
            float t2 = sv * sv;
            t2 += __shfl_xor(t2, 1); t2 += __shfl_xor(t2, 2);
            t2 += __shfl_xor(t2, 4); t2 += __shfl_xor(t2, 8);
            const float scale = t2 / (1.0f + t2) / sqrtf(t2 + 1e-7f);
            const float v = scale * sv;
            if (pass == 2) out[(size_t)b * JD + tid] = v;
            else vdot_lds[tid] = (pass == 0) ? v : (vdot_lds[tid] + v);
        }
        __syncthreads();
    }
}

extern "C" void kernel_launch(void* const* d_in, const int* in_sizes, int n_in,
                              void* d_out, int out_size, void* d_ws, size_t ws_size,
                              hipStream_t stream) {
    const float* x = (const float*)d_in[0];
    const float* W = (const float*)d_in[1];
    float* out = (float*)d_out;

    if (ws_size >= WS_NEED) {
        unsigned short* wht = (unsigned short*)d_ws;
        unsigned short* xht = (unsigned short*)((char*)d_ws + WHT_BYTES);
        float* s_part = (float*)((char*)d_ws + WHT_BYTES + XHT_BYTES);
        float* vdot_g = (float*)((char*)d_ws + WHT_BYTES + XHT_BYTES + SP_BYTES);
        int*   cnt    = (int*)((char*)d_ws + WHT_BYTES + XHT_BYTES + SP_BYTES + VD_BYTES);

        prep_all<<<PREPW_BLOCKS + PREPX_BLOCKS, 256, 0, stream>>>(
            x, W, (unsigned*)wht, (unsigned*)xht, cnt);

        const dim3 gR(NSLAB, 16);
        caps_pass<0><<<gR, 256, 0, stream>>>(wht, xht, vdot_g, s_part, out, cnt);
        caps_pass<1><<<gR, 256, 0, stream>>>(wht, xht, vdot_g, s_part, out, cnt);
        caps_pass<2><<<gR, 256, 0, stream>>>(wht, xht, vdot_g, s_part, out, cnt);
    } else {
        caps_routing_kernel<<<B_TOT, FB_THREADS, 0, stream>>>(x, W, out);
    }
}

// Round 13
// 124.717 us; speedup vs baseline: 3.1443x; 3.1443x over previous
//
#include <hip/hip_runtime.h>
#include <math.h>

// CapsuleLayer dynamic routing. B=256, IN=1152, K=8, J=10, D=16, 3 passes.
//
// 4 kernels, split-K last-block fusion WITHOUT device fences (r12 lesson:
// __threadfence = per-block L2 writeback = catastrophic):
//  prep_all : (r7-r11-verified) W -> wht bf16 [i][jd][k]*0.25 (k-replication
//             trick: 4 K-quads read the same 8-k fragment -> u = 4*(x*W/4));
//             x -> xht bf16 [i][b][k]. Zeroes last-block counters.
//  caps_pass<P>: grid (48 i-slabs x 16 b-tiles), 256 thr = 4 waves.
//             r11-verified compute (MFMA fragment math, in-lane softmax
//             without max-sub, 4-wave LDS tree reduce). Slab store via
//             RELAXED AGENT-scope atomic stores (write-through, L2-bypass,
//             visible device-wide after vmcnt drain — no wbl2). Then
//             s_waitcnt vmcnt(0) + barrier + relaxed agent fetch_add; the
//             48th block per btile re-reads the 48 slabs with relaxed agent
//             atomic LOADS (L2-bypass, never stale), reduces in fixed order
//             (deterministic), squashes -> vdot_g (P0: =v0, P1: +=v1) or
//             out (P2). vdot_g handoff between passes relies on the normal
//             kernel-boundary release/acquire.
// Algebra: logits at pass t = (sum of previous v)·u_hat; pass 0 c = 0.1.

typedef float f32x4 __attribute__((ext_vector_type(4)));
typedef short bf16x8 __attribute__((ext_vector_type(8)));

#define B_TOT 256
#define IN_CAPS 1152
#define OUT_CAPS 10
#define JD 160

#define NSLAB 48
#define IPB 24             // i per block
#define CHI 12             // i per W chunk (2 chunks)
#define REDS 164

#define WHT_BYTES (1152ull * 160 * 8 * 2)             // 2,949,120
#define XHT_BYTES (1152ull * 256 * 8 * 2)             // 4,718,592
#define SP_BYTES  ((size_t)NSLAB * B_TOT * JD * 4)    // 7,864,320
#define VD_BYTES  ((size_t)B_TOT * JD * 4)            // 163,840
#define CNT_BYTES (3 * 16 * 4)
#define WS_NEED   (WHT_BYTES + XHT_BYTES + SP_BYTES + VD_BYTES + CNT_BYTES)

static __device__ __forceinline__ unsigned f2bf(float f) {
    unsigned u = __float_as_uint(f);
    return (u + 0x7FFFu + ((u >> 16) & 1u)) >> 16;
}

static __device__ __forceinline__ unsigned long long packf2(float a, float b) {
    return (unsigned long long)__float_as_uint(a)
         | ((unsigned long long)__float_as_uint(b) << 32);
}

// ---------------- coalesced preps (r7-r11-verified) ----------------
#define PREPW_BLOCKS 288   // 4 i each
#define PREPX_BLOCKS 288   // 16 i x 64 b each

__global__ __launch_bounds__(256)
void prep_all(const float* __restrict__ x, const float* __restrict__ W,
              unsigned* __restrict__ whu, unsigned* __restrict__ xhu,
              int* __restrict__ cnt) {
    __shared__ __align__(16) float lds[64 * 132];   // 33,792 B
    const int bid = blockIdx.x, t = threadIdx.x;

    if (bid == 0 && t < 48) cnt[t] = 0;             // reset last-block counters

    if (bid < PREPW_BLOCKS) {
        const int i0 = bid * 4;
        const f32x4* src = (const f32x4*)(W + (size_t)i0 * 1280);
        for (int c = t; c < 1280; c += 256)
            *(f32x4*)(lds + c * 4) = src[c];          // coalesced read
        __syncthreads();
        for (int c = t; c < 2560; c += 256) {
            const int i_l = c / 640, p = c % 640;
            const int jd = p >> 2, kp = p & 3;        // k = 2*kp
            const int j = jd >> 4, d = jd & 15;
            const float* base = lds + i_l * 1280 + j * 128 + d;
            const unsigned lo = f2bf(base[(2 * kp) * 16] * 0.25f);
            const unsigned hi = f2bf(base[(2 * kp + 1) * 16] * 0.25f);
            whu[(size_t)i0 * 640 + c] = lo | (hi << 16);   // coalesced write
        }
    } else {
        const int bx = bid - PREPW_BLOCKS;
        const int it = bx >> 2;          // 72 i-tiles
        const int bt = bx & 3;           // 4 b-tiles of 64
        const int i0 = it * 16, b0 = bt * 64;
        for (int c = t; c < 2048; c += 256) {
            const int bl = c >> 5, cf = c & 31;
            f32x4 v = *(const f32x4*)(x + (size_t)(b0 + bl) * 9216 + i0 * 8 + cf * 4);
            *(f32x4*)(lds + bl * 132 + cf * 4) = v;   // coalesced read
        }
        __syncthreads();
        for (int c = t; c < 1024; c += 256) {
            const int i_l = c >> 6, b_l = c & 63;
            const float* r = lds + b_l * 132 + i_l * 8;
            uint4 o;
            o.x = f2bf(r[0]) | (f2bf(r[1]) << 16);
            o.y = f2bf(r[2]) | (f2bf(r[3]) << 16);
            o.z = f2bf(r[4]) | (f2bf(r[5]) << 16);
            o.w = f2bf(r[6]) | (f2bf(r[7]) << 16);
            ((uint4*)xhu)[(size_t)(i0 + i_l) * 256 + b0 + b_l] = o;  // 1KB runs
        }
    }
}

// ---------------- routing pass with fence-free fused squash ----------------
template<int PASS>
__global__ __launch_bounds__(256, 3)
void caps_pass(const unsigned short* __restrict__ wht,
               const unsigned short* __restrict__ xht,
               float* __restrict__ vdot_g,
               float* __restrict__ s_part,
               float* __restrict__ out,
               int* __restrict__ cnt) {
    __shared__ __align__(16) unsigned short wsl[CHI * 160 * 8];  // 30,720 B
    __shared__ __align__(16) unsigned short xsl[IPB * 16 * 8];   //  6,144 B
    __shared__ int isLast;
    float* red = (float*)wsl;   // aliased after compute (needs 20,992 B)

    const int t = threadIdx.x;
    const int l = t & 63;
    const int w = t >> 6;              // wave 0..3 (splits i)
    const int m = l & 15;              // b in tile / A-row / C-col
    const int q = l >> 4;              // k-quad (replicated) / d-quad (out)
    const int islab = blockIdx.x;      // 0..47
    const int btile = blockIdx.y;      // 0..15
    const int b0 = btile * 16;
    const int b = b0 + m;
    const int i0 = islab * IPB;

    // ---- stage x slab once: 24 i x 16 b ----
    {
        uint4* dX = (uint4*)xsl;
        for (int c = t; c < IPB * 16; c += 256) {
            const int il = c >> 4, bl = c & 15;
            dX[c] = ((const uint4*)xht)[(size_t)(i0 + il) * 256 + b0 + bl];
        }
    }

    // vdot fragments (i-invariant) from global (cross-kernel coherent), PASS>=1
    f32x4 vd[10];
    if (PASS > 0) {
        #pragma unroll
        for (int jt = 0; jt < 10; ++jt)
            vd[jt] = *(const f32x4*)(vdot_g + (size_t)b * JD + jt * 16 + q * 4);
    }

    f32x4 s[10];
    #pragma unroll
    for (int jt = 0; jt < 10; ++jt) s[jt] = (f32x4){0.f, 0.f, 0.f, 0.f};

    // ---- 2 W chunks of 12 i ----
    #pragma unroll 1
    for (int ch = 0; ch < 2; ++ch) {
        __syncthreads();    // prev chunk reads done (also orders xsl writes)
        {
            const uint4* srcW = (const uint4*)wht + (size_t)(i0 + ch * CHI) * 160;
            uint4* dW = (uint4*)wsl;
            for (int c = t; c < CHI * 160; c += 256) dW[c] = srcW[c];
        }
        __syncthreads();

        #pragma unroll 1
        for (int ii = 0; ii < 3; ++ii) {
            const int il = w * 3 + ii;                 // 0..11 within chunk
            const bf16x8 xb = *(const bf16x8*)(xsl + ((ch * CHI + il) * 16 + m) * 8);

            if (PASS == 0) {
                #pragma unroll
                for (int jt = 0; jt < 10; ++jt) {
                    const bf16x8 af = *(const bf16x8*)(wsl + (il * 160 + jt * 16 + m) * 8);
                    s[jt] = __builtin_amdgcn_mfma_f32_16x16x32_bf16(af, xb, s[jt], 0, 0, 0);
                }
            } else {
                f32x4 u[10];
                #pragma unroll
                for (int jt = 0; jt < 10; ++jt) {
                    const bf16x8 af = *(const bf16x8*)(wsl + (il * 160 + jt * 16 + m) * 8);
                    u[jt] = __builtin_amdgcn_mfma_f32_16x16x32_bf16(
                                af, xb, (f32x4){0.f, 0.f, 0.f, 0.f}, 0, 0, 0);
                }
                float L[10];
                #pragma unroll
                for (int jt = 0; jt < 10; ++jt) {
                    const f32x4 p = vd[jt] * u[jt];
                    float e = (p.x + p.y) + (p.z + p.w);
                    e += __shfl_xor(e, 16);
                    e += __shfl_xor(e, 32);
                    L[jt] = e;
                }
                float Z = 0.f;
                #pragma unroll
                for (int jt = 0; jt < 10; ++jt) { L[jt] = __expf(L[jt]); Z += L[jt]; }
                const float inv = 1.0f / Z;
                #pragma unroll
                for (int jt = 0; jt < 10; ++jt) s[jt] += (L[jt] * inv) * u[jt];
            }
        }
    }

    if (PASS == 0) {
        #pragma unroll
        for (int jt = 0; jt < 10; ++jt) s[jt] *= 0.1f;
    }

    // ---- 4-wave tree reduce through LDS (red aliases wsl) ----
    __syncthreads();
    if (w >= 2) {
        float* rp = red + (w - 2) * (16 * REDS) + m * REDS + q * 4;
        #pragma unroll
        for (int jt = 0; jt < 10; ++jt) *(f32x4*)(rp + jt * 16) = s[jt];
    }
    __syncthreads();
    if (w < 2) {
        const float* rp = red + w * (16 * REDS) + m * REDS + q * 4;
        #pragma unroll
        for (int jt = 0; jt < 10; ++jt) s[jt] += *(const f32x4*)(rp + jt * 16);
    }
    __syncthreads();
    if (w == 1) {
        float* rp = red + m * REDS + q * 4;
        #pragma unroll
        for (int jt = 0; jt < 10; ++jt) *(f32x4*)(rp + jt * 16) = s[jt];
    }
    __syncthreads();
    if (w == 0) {
        const float* rp = red + m * REDS + q * 4;
        #pragma unroll
        for (int jt = 0; jt < 10; ++jt) s[jt] += *(const f32x4*)(rp + jt * 16);
        // slab store: RELAXED AGENT atomics (write-through, L2-bypass) —
        // globally visible once vmcnt drains, no cache flush needed.
        unsigned long long* sp =
            (unsigned long long*)(s_part + ((size_t)islab * B_TOT + b) * JD);
        #pragma unroll
        for (int jt = 0; jt < 10; ++jt) {
            __hip_atomic_store(sp + (jt * 16 + q * 4) / 2, packf2(s[jt].x, s[jt].y),
                               __ATOMIC_RELAXED, __HIP_MEMORY_SCOPE_AGENT);
            __hip_atomic_store(sp + (jt * 16 + q * 4) / 2 + 1, packf2(s[jt].z, s[jt].w),
                               __ATOMIC_RELAXED, __HIP_MEMORY_SCOPE_AGENT);
        }
    }

    // ---- fence-free last-block squash ----
    asm volatile("s_waitcnt vmcnt(0)" ::: "memory");   // drain our stores
    __syncthreads();                                   // all lanes drained
    if (t == 0)
        isLast = (__hip_atomic_fetch_add(&cnt[PASS * 16 + btile], 1,
                    __ATOMIC_RELAXED, __HIP_MEMORY_SCOPE_AGENT) == NSLAB - 1);
    __syncthreads();
    if (!isLast) return;

    // 2560 outputs for this btile; thread handles 10 (coalesced), fixed order.
    // Reads are RELAXED AGENT atomic loads: bypass L2 -> never stale.
    float acc[10];
    #pragma unroll
    for (int c = 0; c < 10; ++c) acc[c] = 0.f;
    #pragma unroll 4
    for (int p = 0; p < NSLAB; ++p) {
        const float* sp = s_part + (size_t)p * (B_TOT * JD) + b0 * JD;
        #pragma unroll
        for (int c = 0; c < 10; ++c)
            acc[c] += __hip_atomic_load(&sp[c * 256 + t],
                        __ATOMIC_RELAXED, __HIP_MEMORY_SCOPE_AGENT);
    }
    #pragma unroll
    for (int c = 0; c < 10; ++c) {
        const float sv = acc[c];
        float tt = sv * sv;                        // d = (c*256+t)&15 = t&15
        tt += __shfl_xor(tt, 1);
        tt += __shfl_xor(tt, 2);
        tt += __shfl_xor(tt, 4);
        tt += __shfl_xor(tt, 8);
        const float sc = tt / (1.0f + tt) / sqrtf(tt + 1e-7f);
        const float v = sc * sv;
        const int e = b0 * JD + c * 256 + t;
        if (PASS == 0)      vdot_g[e] = v;         // consumed next kernel
        else if (PASS == 1) vdot_g[e] += v;
        else                out[e] = v;
    }
}

// ---------- fallback: round-1 fused kernel (ws too small; shouldn't happen) ----------
#define FB_NGROUPS 32
#define FB_THREADS (FB_NGROUPS * 16)
#define FB_ITERS (IN_CAPS / FB_NGROUPS)
__global__ __launch_bounds__(FB_THREADS)
void caps_routing_kernel(const float* __restrict__ x, const float* __restrict__ W,
                         float* __restrict__ out) {
    __shared__ __align__(16) float xsf[IN_CAPS * 8];
    __shared__ float sredf[FB_NGROUPS * JD];
    __shared__ float vdot_lds[JD];
    const int b = blockIdx.x, tid = threadIdx.x;
    const int g = tid >> 4, d = tid & 15;
    {
        const float4* xg = reinterpret_cast<const float4*>(x + (size_t)b * IN_CAPS * 8);
        float4* xl = reinterpret_cast<float4*>(xsf);
        for (int t = tid; t < IN_CAPS * 2; t += FB_THREADS) xl[t] = xg[t];
    }
    __syncthreads();
    for (int pass = 0; pass < 3; ++pass) {
        float vdot_reg[OUT_CAPS];
        if (pass > 0) {
            #pragma unroll
            for (int j = 0; j < OUT_CAPS; ++j) vdot_reg[j] = vdot_lds[j * 16 + d];
        }
        float s_loc[OUT_CAPS];
        #pragma unroll
        for (int j = 0; j < OUT_CAPS; ++j) s_loc[j] = 0.f;
        for (int it = 0; it < FB_ITERS; ++it) {
            const int i = it * FB_NGROUPS + g;
            float xk[8];
            {
                const float4* xr = reinterpret_cast<const float4*>(xsf + i * 8);
                float4 a0 = xr[0], a1 = xr[1];
                xk[0]=a0.x; xk[1]=a0.y; xk[2]=a0.z; xk[3]=a0.w;
                xk[4]=a1.x; xk[5]=a1.y; xk[6]=a1.z; xk[7]=a1.w;
            }
            const float* wpf = W + (size_t)i * 1280 + d;
            float u[OUT_CAPS];
            #pragma unroll
            for (int j = 0; j < OUT_CAPS; ++j) {
                float acc = 0.f;
                #pragma unroll
                for (int k = 0; k < 8; ++k) acc = fmaf(xk[k], wpf[j * 128 + k * 16], acc);
                u[j] = acc;
            }
            if (pass == 0) {
                #pragma unroll
                for (int j = 0; j < OUT_CAPS; ++j) s_loc[j] = fmaf(0.1f, u[j], s_loc[j]);
            } else {
                float logit[OUT_CAPS];
                #pragma unroll
                for (int j = 0; j < OUT_CAPS; ++j) {
                    float t2 = vdot_reg[j] * u[j];
                    t2 += __shfl_xor(t2, 1); t2 += __shfl_xor(t2, 2);
                    t2 += __shfl_xor(t2, 4); t2 += __shfl_xor(t2, 8);
                    logit[j] = t2;
                }
                float mm = logit[0];
                #pragma unroll
                for (int j = 1; j < OUT_CAPS; ++j) mm = fmaxf(mm, logit[j]);
                float Z = 0.f, e[OUT_CAPS];
                #pragma unroll
                for (int j = 0; j < OUT_CAPS; ++j) { e[j] = expf(logit[j] - mm); Z += e[j]; }
                const float invZ = 1.0f / Z;
                #pragma unroll
                for (int j = 0; j < OUT_CAPS; ++j) s_loc[j] = fmaf(e[j] * invZ, u[j], s_loc[j]);
            }
        }
        #pragma unroll
        for (int j = 0; j < OUT_CAPS; ++j) sredf[g * JD + j * 16 + d] = s_loc[j];
        __syncthreads();
        if (tid < JD) {
            float sv = 0.f;
            #pragma unroll 8
            for (int gg = 0; gg < FB_NGROUPS; ++gg) sv += sredf[gg * JD + tid];
            float t2 = sv * sv;
            t2 += __shfl_xor(t2, 1); t2 += __shfl_xor(t2, 2);
            t2 += __shfl_xor(t2, 4); t2 += __shfl_xor(t2, 8);
            const float scale = t2 / (1.0f + t2) / sqrtf(t2 + 1e-7f);
            const float v = scale * sv;
            if (pass == 2) out[(size_t)b * JD + tid] = v;
            else vdot_lds[tid] = (pass == 0) ? v : (vdot_lds[tid] + v);
        }
        __syncthreads();
    }
}

extern "C" void kernel_launch(void* const* d_in, const int* in_sizes, int n_in,
                              void* d_out, int out_size, void* d_ws, size_t ws_size,
                              hipStream_t stream) {
    const float* x = (const float*)d_in[0];
    const float* W = (const float*)d_in[1];
    float* out = (float*)d_out;

    if (ws_size >= WS_NEED) {
        unsigned short* wht = (unsigned short*)d_ws;
        unsigned short* xht = (unsigned short*)((char*)d_ws + WHT_BYTES);
        float* s_part = (float*)((char*)d_ws + WHT_BYTES + XHT_BYTES);
        float* vdot_g = (float*)((char*)d_ws + WHT_BYTES + XHT_BYTES + SP_BYTES);
        int*   cnt    = (int*)((char*)d_ws + WHT_BYTES + XHT_BYTES + SP_BYTES + VD_BYTES);

        prep_all<<<PREPW_BLOCKS + PREPX_BLOCKS, 256, 0, stream>>>(
            x, W, (unsigned*)wht, (unsigned*)xht, cnt);

        const dim3 gR(NSLAB, 16);
        caps_pass<0><<<gR, 256, 0, stream>>>(wht, xht, vdot_g, s_part, out, cnt);
        caps_pass<1><<<gR, 256, 0, stream>>>(wht, xht, vdot_g, s_part, out, cnt);
        caps_pass<2><<<gR, 256, 0, stream>>>(wht, xht, vdot_g, s_part, out, cnt);
    } else {
        caps_routing_kernel<<<B_TOT, FB_THREADS, 0, stream>>>(x, W, out);
    }
}

// Round 14
// 70.092 us; speedup vs baseline: 5.5947x; 1.7793x over previous
//
#include <hip/hip_runtime.h>
#include <math.h>

// CapsuleLayer dynamic routing. B=256, IN=1152, K=8, J=10, D=16, 3 passes.
//
// 5 kernels; global reduction via device-scope memory-side f32 atomicAdd
// (no fences/flushes — r12/r13 lesson: threadfence & UC-atomics are 30-50us;
// kernel boundary + memory-side atomics are the cheap primitives):
//  prep_all : (r7-r11-verified) W -> wht bf16 [i][jd][k]*0.25 (k-replication
//             trick: 4 K-quads read the same 8-k fragment -> u = 4*(x*W/4));
//             x -> xht bf16 [i][b][k]. Zeroes s_sum0.
//  caps_pass<P>: grid (48 i-slabs x 16 b-tiles), 256 thr = 4 waves.
//             P>0 preamble: block redundantly squashes s_sum (10KB, L2-hit)
//             for its own 16 batches -> vdot in LDS (r9-verified 16-lane
//             shfl pattern; P2 adds v0+v1). Then r11-verified compute (MFMA
//             fragment math, in-lane softmax without max-sub, 4-wave LDS
//             tree reduce). w==0 atomicAdds partial s into s_sum[jd][b]
//             (16-consecutive addresses per wave-quad). islab==0 zeroes the
//             NEXT pass's s_sum (visible at kernel boundary).
//  sq_final : squash s_sum2 -> out.
// FP-atomic order varies run-to-run (~1e-6) — tolerance-validated.
// Algebra: logits at pass t = (sum of previous v)·u_hat; pass 0 c = 0.1.

typedef float f32x4 __attribute__((ext_vector_type(4)));
typedef short bf16x8 __attribute__((ext_vector_type(8)));

#define B_TOT 256
#define IN_CAPS 1152
#define OUT_CAPS 10
#define JD 160

#define NSLAB 48
#define IPB 24             // i per block
#define CHI 12             // i per W chunk (2 chunks)
#define REDS 164

#define WHT_BYTES (1152ull * 160 * 8 * 2)             // 2,949,120
#define XHT_BYTES (1152ull * 256 * 8 * 2)             // 4,718,592
#define SSUM_BYTES ((size_t)B_TOT * JD * 4)           // 163,840
#define WS_NEED   (WHT_BYTES + XHT_BYTES + 3 * SSUM_BYTES)

static __device__ __forceinline__ unsigned f2bf(float f) {
    unsigned u = __float_as_uint(f);
    return (u + 0x7FFFu + ((u >> 16) & 1u)) >> 16;
}

// ---------------- coalesced preps (r7-r11-verified) ----------------
#define PREPW_BLOCKS 288   // 4 i each
#define PREPX_BLOCKS 288   // 16 i x 64 b each

__global__ __launch_bounds__(256)
void prep_all(const float* __restrict__ x, const float* __restrict__ W,
              unsigned* __restrict__ whu, unsigned* __restrict__ xhu,
              float* __restrict__ s0) {
    __shared__ __align__(16) float lds[64 * 132];   // 33,792 B
    const int bid = blockIdx.x, t = threadIdx.x;

    if (bid < 160) s0[bid * 256 + t] = 0.f;         // zero s_sum0 (replay-safe)

    if (bid < PREPW_BLOCKS) {
        const int i0 = bid * 4;
        const f32x4* src = (const f32x4*)(W + (size_t)i0 * 1280);
        for (int c = t; c < 1280; c += 256)
            *(f32x4*)(lds + c * 4) = src[c];          // coalesced read
        __syncthreads();
        for (int c = t; c < 2560; c += 256) {
            const int i_l = c / 640, p = c % 640;
            const int jd = p >> 2, kp = p & 3;        // k = 2*kp
            const int j = jd >> 4, d = jd & 15;
            const float* base = lds + i_l * 1280 + j * 128 + d;
            const unsigned lo = f2bf(base[(2 * kp) * 16] * 0.25f);
            const unsigned hi = f2bf(base[(2 * kp + 1) * 16] * 0.25f);
            whu[(size_t)i0 * 640 + c] = lo | (hi << 16);   // coalesced write
        }
    } else {
        const int bx = bid - PREPW_BLOCKS;
        const int it = bx >> 2;          // 72 i-tiles
        const int bt = bx & 3;           // 4 b-tiles of 64
        const int i0 = it * 16, b0 = bt * 64;
        for (int c = t; c < 2048; c += 256) {
            const int bl = c >> 5, cf = c & 31;
            f32x4 v = *(const f32x4*)(x + (size_t)(b0 + bl) * 9216 + i0 * 8 + cf * 4);
            *(f32x4*)(lds + bl * 132 + cf * 4) = v;   // coalesced read
        }
        __syncthreads();
        for (int c = t; c < 1024; c += 256) {
            const int i_l = c >> 6, b_l = c & 63;
            const float* r = lds + b_l * 132 + i_l * 8;
            uint4 o;
            o.x = f2bf(r[0]) | (f2bf(r[1]) << 16);
            o.y = f2bf(r[2]) | (f2bf(r[3]) << 16);
            o.z = f2bf(r[4]) | (f2bf(r[5]) << 16);
            o.w = f2bf(r[6]) | (f2bf(r[7]) << 16);
            ((uint4*)xhu)[(size_t)(i0 + i_l) * 256 + b0 + b_l] = o;  // 1KB runs
        }
    }
}

// ---------------- routing pass, atomicAdd-fused ----------------
// s_sum layout: [jd][b] (jd = j*16+d major) -> wave atomics hit 16
// consecutive addresses per (jt, q, component).
template<int PASS>
__global__ __launch_bounds__(256, 3)
void caps_pass(const unsigned short* __restrict__ wht,
               const unsigned short* __restrict__ xht,
               const float* __restrict__ sp0,   // s_sum of pass0 (P>=1)
               const float* __restrict__ sp1,   // s_sum of pass1 (P==2)
               float* __restrict__ s_cur,       // accumulate here
               float* __restrict__ s_next) {    // zero for next pass (P<2)
    __shared__ __align__(16) unsigned short wsl[CHI * 160 * 8];  // 30,720 B
    __shared__ __align__(16) unsigned short xsl[IPB * 16 * 8];   //  6,144 B
    float* red = (float*)wsl;   // aliased: vdl (preamble) + tree reduce
    float* vdl = (float*)wsl;   // 16 x REDS floats = 10,496 B

    const int t = threadIdx.x;
    const int l = t & 63;
    const int w = t >> 6;              // wave 0..3 (splits i)
    const int m = l & 15;              // b in tile / A-row / C-col
    const int q = l >> 4;              // k-quad (replicated) / d-quad (out)
    const int islab = blockIdx.x;      // 0..47
    const int btile = blockIdx.y;      // 0..15
    const int b0 = btile * 16;
    const int i0 = islab * IPB;

    // ---- stage x slab once: 24 i x 16 b ----
    {
        uint4* dX = (uint4*)xsl;
        for (int c = t; c < IPB * 16; c += 256) {
            const int il = c >> 4, bl = c & 15;
            dX[c] = ((const uint4*)xht)[(size_t)(i0 + il) * 256 + b0 + bl];
        }
    }

    // ---- zero next pass's s_sum (islab==0 blocks; visible at boundary) ----
    if (PASS < 2 && islab == 0) {
        for (int c = t; c < 2560; c += 256) {
            const int jd = c >> 4, bl = c & 15;
            s_next[jd * 256 + b0 + bl] = 0.f;
        }
    }

    // ---- P>0 preamble: redundant per-block squash -> vdl -> vd regs ----
    f32x4 vd[10];
    if (PASS > 0) {
        const int b_l = t >> 4, dd = t & 15;
        #pragma unroll
        for (int jj = 0; jj < 10; ++jj) {
            float sv = sp0[(jj * 16 + dd) * 256 + b0 + b_l];
            float tt = sv * sv;
            tt += __shfl_xor(tt, 1);
            tt += __shfl_xor(tt, 2);
            tt += __shfl_xor(tt, 4);
            tt += __shfl_xor(tt, 8);
            float vv = (tt / (1.0f + tt) / sqrtf(tt + 1e-7f)) * sv;
            if (PASS == 2) {
                float s1 = sp1[(jj * 16 + dd) * 256 + b0 + b_l];
                float t1 = s1 * s1;
                t1 += __shfl_xor(t1, 1);
                t1 += __shfl_xor(t1, 2);
                t1 += __shfl_xor(t1, 4);
                t1 += __shfl_xor(t1, 8);
                vv += (t1 / (1.0f + t1) / sqrtf(t1 + 1e-7f)) * s1;
            }
            vdl[b_l * REDS + jj * 16 + dd] = vv;
        }
        __syncthreads();
        #pragma unroll
        for (int jt = 0; jt < 10; ++jt)
            vd[jt] = *(const f32x4*)(vdl + m * REDS + jt * 16 + q * 4);
    }

    f32x4 s[10];
    #pragma unroll
    for (int jt = 0; jt < 10; ++jt) s[jt] = (f32x4){0.f, 0.f, 0.f, 0.f};

    // ---- 2 W chunks of 12 i ----
    #pragma unroll 1
    for (int ch = 0; ch < 2; ++ch) {
        __syncthreads();    // vdl dead / prev chunk reads done / xsl ordered
        {
            const uint4* srcW = (const uint4*)wht + (size_t)(i0 + ch * CHI) * 160;
            uint4* dW = (uint4*)wsl;
            for (int c = t; c < CHI * 160; c += 256) dW[c] = srcW[c];
        }
        __syncthreads();

        #pragma unroll 1
        for (int ii = 0; ii < 3; ++ii) {
            const int il = w * 3 + ii;                 // 0..11 within chunk
            const bf16x8 xb = *(const bf16x8*)(xsl + ((ch * CHI + il) * 16 + m) * 8);

            if (PASS == 0) {
                #pragma unroll
                for (int jt = 0; jt < 10; ++jt) {
                    const bf16x8 af = *(const bf16x8*)(wsl + (il * 160 + jt * 16 + m) * 8);
                    s[jt] = __builtin_amdgcn_mfma_f32_16x16x32_bf16(af, xb, s[jt], 0, 0, 0);
                }
            } else {
                f32x4 u[10];
                #pragma unroll
                for (int jt = 0; jt < 10; ++jt) {
                    const bf16x8 af = *(const bf16x8*)(wsl + (il * 160 + jt * 16 + m) * 8);
                    u[jt] = __builtin_amdgcn_mfma_f32_16x16x32_bf16(
                                af, xb, (f32x4){0.f, 0.f, 0.f, 0.f}, 0, 0, 0);
                }
                float L[10];
                #pragma unroll
                for (int jt = 0; jt < 10; ++jt) {
                    const f32x4 p = vd[jt] * u[jt];
                    float e = (p.x + p.y) + (p.z + p.w);
                    e += __shfl_xor(e, 16);
                    e += __shfl_xor(e, 32);
                    L[jt] = e;
                }
                float Z = 0.f;
                #pragma unroll
                for (int jt = 0; jt < 10; ++jt) { L[jt] = __expf(L[jt]); Z += L[jt]; }
                const float inv = 1.0f / Z;
                #pragma unroll
                for (int jt = 0; jt < 10; ++jt) s[jt] += (L[jt] * inv) * u[jt];
            }
        }
    }

    if (PASS == 0) {
        #pragma unroll
        for (int jt = 0; jt < 10; ++jt) s[jt] *= 0.1f;
    }

    // ---- 4-wave tree reduce through LDS (red aliases wsl) ----
    __syncthreads();
    if (w >= 2) {
        float* rp = red + (w - 2) * (16 * REDS) + m * REDS + q * 4;
        #pragma unroll
        for (int jt = 0; jt < 10; ++jt) *(f32x4*)(rp + jt * 16) = s[jt];
    }
    __syncthreads();
    if (w < 2) {
        const float* rp = red + w * (16 * REDS) + m * REDS + q * 4;
        #pragma unroll
        for (int jt = 0; jt < 10; ++jt) s[jt] += *(const f32x4*)(rp + jt * 16);
    }
    __syncthreads();
    if (w == 1) {
        float* rp = red + m * REDS + q * 4;
        #pragma unroll
        for (int jt = 0; jt < 10; ++jt) *(f32x4*)(rp + jt * 16) = s[jt];
    }
    __syncthreads();
    if (w == 0) {
        const float* rp = red + m * REDS + q * 4;
        #pragma unroll
        for (int jt = 0; jt < 10; ++jt) s[jt] += *(const f32x4*)(rp + jt * 16);
        // memory-side device-scope atomics; [jd][b] -> 16-consecutive per quad
        #pragma unroll
        for (int jt = 0; jt < 10; ++jt) {
            atomicAdd(&s_cur[(jt * 16 + q * 4 + 0) * 256 + b0 + m], s[jt].x);
            atomicAdd(&s_cur[(jt * 16 + q * 4 + 1) * 256 + b0 + m], s[jt].y);
            atomicAdd(&s_cur[(jt * 16 + q * 4 + 2) * 256 + b0 + m], s[jt].z);
            atomicAdd(&s_cur[(jt * 16 + q * 4 + 3) * 256 + b0 + m], s[jt].w);
        }
    }
}

// ---------------- final squash: s_sum2 -> out ----------------
__global__ __launch_bounds__(256)
void sq_final(const float* __restrict__ s2, float* __restrict__ out) {
    const int bid = blockIdx.x;        // 0..159
    const int t = threadIdx.x;
    const int j = bid % 10, b_hi = bid / 10;
    const int b = b_hi * 16 + (t >> 4);
    const int d = t & 15;
    const float sv = s2[(j * 16 + d) * 256 + b];
    float tt = sv * sv;
    tt += __shfl_xor(tt, 1);
    tt += __shfl_xor(tt, 2);
    tt += __shfl_xor(tt, 4);
    tt += __shfl_xor(tt, 8);
    const float sc = tt / (1.0f + tt) / sqrtf(tt + 1e-7f);
    out[b * JD + j * 16 + d] = sc * sv;
}

// ---------- fallback: round-1 fused kernel (ws too small; shouldn't happen) ----------
#define FB_NGROUPS 32
#define FB_THREADS (FB_NGROUPS * 16)
#define FB_ITERS (IN_CAPS / FB_NGROUPS)
__global__ __launch_bounds__(FB_THREADS)
void caps_routing_kernel(const float* __restrict__ x, const float* __restrict__ W,
                         float* __restrict__ out) {
    __shared__ __align__(16) float xsf[IN_CAPS * 8];
    __shared__ float sredf[FB_NGROUPS * JD];
    __shared__ float vdot_lds[JD];
    const int b = blockIdx.x, tid = threadIdx.x;
    const int g = tid >> 4, d = tid & 15;
    {
        const float4* xg = reinterpret_cast<const float4*>(x + (size_t)b * IN_CAPS * 8);
        float4* xl = reinterpret_cast<float4*>(xsf);
        for (int t = tid; t < IN_CAPS * 2; t += FB_THREADS) xl[t] = xg[t];
    }
    __syncthreads();
    for (int pass = 0; pass < 3; ++pass) {
        float vdot_reg[OUT_CAPS];
        if (pass > 0) {
            #pragma unroll
            for (int j = 0; j < OUT_CAPS; ++j) vdot_reg[j] = vdot_lds[j * 16 + d];
        }
        float s_loc[OUT_CAPS];
        #pragma unroll
        for (int j = 0; j < OUT_CAPS; ++j) s_loc[j] = 0.f;
        for (int it = 0; it < FB_ITERS; ++it) {
            const int i = it * FB_NGROUPS + g;
            float xk[8];
            {
                const float4* xr = reinterpret_cast<const float4*>(xsf + i * 8);
                float4 a0 = xr[0], a1 = xr[1];
                xk[0]=a0.x; xk[1]=a0.y; xk[2]=a0.z; xk[3]=a0.w;
                xk[4]=a1.x; xk[5]=a1.y; xk[6]=a1.z; xk[7]=a1.w;
            }
            const float* wpf = W + (size_t)i * 1280 + d;
            float u[OUT_CAPS];
            #pragma unroll
            for (int j = 0; j < OUT_CAPS; ++j) {
                float acc = 0.f;
                #pragma unroll
                for (int k = 0; k < 8; ++k) acc = fmaf(xk[k], wpf[j * 128 + k * 16], acc);
                u[j] = acc;
            }
            if (pass == 0) {
                #pragma unroll
                for (int j = 0; j < OUT_CAPS; ++j) s_loc[j] = fmaf(0.1f, u[j], s_loc[j]);
            } else {
                float logit[OUT_CAPS];
                #pragma unroll
                for (int j = 0; j < OUT_CAPS; ++j) {
                    float t2 = vdot_reg[j] * u[j];
                    t2 += __shfl_xor(t2, 1); t2 += __shfl_xor(t2, 2);
                    t2 += __shfl_xor(t2, 4); t2 += __shfl_xor(t2, 8);
                    logit[j] = t2;
                }
                float mm = logit[0];
                #pragma unroll
                for (int j = 1; j < OUT_CAPS; ++j) mm = fmaxf(mm, logit[j]);
                float Z = 0.f, e[OUT_CAPS];
                #pragma unroll
                for (int j = 0; j < OUT_CAPS; ++j) { e[j] = expf(logit[j] - mm); Z += e[j]; }
                const float invZ = 1.0f / Z;
                #pragma unroll
                for (int j = 0; j < OUT_CAPS; ++j) s_loc[j] = fmaf(e[j] * invZ, u[j], s_loc[j]);
            }
        }
        #pragma unroll
        for (int j = 0; j < OUT_CAPS; ++j) sredf[g * JD + j * 16 + d] = s_loc[j];
        __syncthreads();
        if (tid < JD) {
            float sv = 0.f;
            #pragma unroll 8
            for (int gg = 0; gg < FB_NGROUPS; ++gg) sv += sredf[gg * JD + tid];
            float t2 = sv * sv;
            t2 += __shfl_xor(t2, 1); t2 += __shfl_xor(t2, 2);
            t2 += __shfl_xor(t2, 4); t2 += __shfl_xor(t2, 8);
            const float scale = t2 / (1.0f + t2) / sqrtf(t2 + 1e-7f);
            const float v = scale * sv;
            if (pass == 2) out[(size_t)b * JD + tid] = v;
            else vdot_lds[tid] = (pass == 0) ? v : (vdot_lds[tid] + v);
        }
        __syncthreads();
    }
}

extern "C" void kernel_launch(void* const* d_in, const int* in_sizes, int n_in,
                              void* d_out, int out_size, void* d_ws, size_t ws_size,
                              hipStream_t stream) {
    const float* x = (const float*)d_in[0];
    const float* W = (const float*)d_in[1];
    float* out = (float*)d_out;

    if (ws_size >= WS_NEED) {
        unsigned short* wht = (unsigned short*)d_ws;
        unsigned short* xht = (unsigned short*)((char*)d_ws + WHT_BYTES);
        float* s0 = (float*)((char*)d_ws + WHT_BYTES + XHT_BYTES);
        float* s1 = (float*)((char*)d_ws + WHT_BYTES + XHT_BYTES + SSUM_BYTES);
        float* s2 = (float*)((char*)d_ws + WHT_BYTES + XHT_BYTES + 2 * SSUM_BYTES);

        prep_all<<<PREPW_BLOCKS + PREPX_BLOCKS, 256, 0, stream>>>(
            x, W, (unsigned*)wht, (unsigned*)xht, s0);

        const dim3 gR(NSLAB, 16);
        caps_pass<0><<<gR, 256, 0, stream>>>(wht, xht, nullptr, nullptr, s0, s1);
        caps_pass<1><<<gR, 256, 0, stream>>>(wht, xht, s0, nullptr, s1, s2);
        caps_pass<2><<<gR, 256, 0, stream>>>(wht, xht, s0, s1, s2, nullptr);
        sq_final<<<160, 256, 0, stream>>>(s2, out);
    } else {
        caps_routing_kernel<<<B_TOT, FB_THREADS, 0, stream>>>(x, W, out);
    }
}